// Round 1
// baseline (194.164 us; speedup 1.0000x reference)
//
#include <hip/hip_runtime.h>
#include <math.h>

// Problem constants
#define NCELLS 207360          // 32*36*36*5
#define NWIN   1024            // B*T = 32*32 targets
#define CONF_BLOCKS 512
#define TOTAL_BLOCKS (NWIN + CONF_BLOCKS)

// ws layout (4-byte slots):
//  f[0]=S_obj_sq  f[1]=S_obj_m1sq  f[2]=loc_sum  f[3]=nme_sum  f[4]=S_all
//  i[5]=n_obj     i[6]=done_counter
//  i[16..16+1024)        winner_flag per target
//  i[16+1024..16+2048)   winner cell index per target

__constant__ float c_anc[5] = {0.24f, 0.12f, 0.08f, 0.28f, 0.15f};

__global__ __launch_bounds__(1024) void k_winners(
    const float* __restrict__ bbox_pred,
    const float* __restrict__ bbox_tgt,
    float* __restrict__ wsf, int* __restrict__ wsi)
{
  __shared__ int skey[1024];
  __shared__ float r0[1024], r1[1024], r2[1024], r3[1024];
  const int tid = threadIdx.x;
  if (tid < 16) wsi[tid] = 0;   // zero accumulators + done counter
  const int b = tid >> 5;
  const int t = tid & 31;

  const float* bt = bbox_tgt + tid * 5;
  float v0 = bt[0], v1 = bt[1], v2 = bt[2], v3 = bt[3], v4 = bt[4];
  bool valid = (v0 + v1 + v2 + v3 + v4) != 0.0f;

  int gi = (int)(v0 * 36.0f);   // truncation toward zero, matches astype(int32) for >=0
  int gj = (int)(v1 * 36.0f);
  float acx = (0.5f + (float)gi) / 36.0f;
  float acy = (0.5f + (float)gj) / 36.0f;

  // corners, mirroring reference arithmetic exactly (fp32)
  float gx1 = (v0 - v2 / 2.0f) * 288.0f;
  float gx2 = (v0 + v2 / 2.0f) * 288.0f;
  float gy1 = (v1 - v3 / 2.0f) * 288.0f;
  float gy2 = (v1 + v3 / 2.0f) * 288.0f;
  float area_g = (gx2 - gx1 + 1.0f) * (gy2 - gy1 + 1.0f);

  int best = 0;
  float best_iou = -3.0e38f;
  for (int a = 0; a < 5; ++a) {
    float aw = c_anc[a];               // anchors are square: aw == ah
    float ax1 = (acx - aw / 2.0f) * 288.0f;
    float ax2 = (acx + aw / 2.0f) * 288.0f;
    float ay1 = (acy - aw / 2.0f) * 288.0f;
    float ay2 = (acy + aw / 2.0f) * 288.0f;
    float ix1 = fmaxf(gx1, ax1);
    float iy1 = fmaxf(gy1, ay1);
    float ix2 = fminf(gx2, ax2);
    float iy2 = fminf(gy2, ay2);
    float inter = (ix2 - ix1 + 1.0f) * (iy2 - iy1 + 1.0f);
    float area_a = (ax2 - ax1 + 1.0f) * (ay2 - ay1 + 1.0f);
    float iou = inter / (area_g + area_a - inter + 1e-16f);
    if (iou > best_iou) { best_iou = iou; best = a; }   // first-max wins, like argmax
  }

  bool inb = valid && (gi >= 0) && (gi < 36) && (gj >= 0) && (gj < 36);
  int key = inb ? ((gj * 36 + gi) * 5 + best) : -1;     // cell key within batch
  skey[tid] = key;
  __syncthreads();

  // winner = highest t among same-batch targets sharing this cell key
  int winner = (key >= 0) ? 1 : 0;
  if (winner) {
    int base = b * 32;
    for (int tt = t + 1; tt < 32; ++tt)
      if (skey[base + tt] == key) { winner = 0; break; }
  }
  int cell = b * 6480 + key;            // global cell index (valid only if winner)
  wsi[16 + tid] = winner;
  wsi[16 + 1024 + tid] = cell;

  // per-winner conf + loc contributions
  float c_sq = 0.f, c_m1 = 0.f, loc = 0.f;
  if (winner) {
    const float* p = bbox_pred + (long)cell * 5;
    float conf = p[4];
    c_sq = conf * conf;
    float cm = conf - 1.0f;
    c_m1 = cm * cm;
    float gs0 = log1pf(v0), gs1 = log1pf(v1), gs2 = log1pf(v2), gs3 = log1pf(v3);
    float gs[4] = {gs0, gs1, gs2, gs3};
    for (int c = 0; c < 4; ++c) {
      float d = p[c] - gs[c];
      float ad = fabsf(d);
      loc += (ad < 1.0f) ? (0.5f * d * d) : (ad - 0.5f);
    }
  }
  r0[tid] = c_sq; r1[tid] = c_m1; r2[tid] = loc; r3[tid] = (float)winner;
  __syncthreads();
  for (int s = 512; s > 0; s >>= 1) {
    if (tid < s) {
      r0[tid] += r0[tid + s];
      r1[tid] += r1[tid + s];
      r2[tid] += r2[tid + s];
      r3[tid] += r3[tid + s];
    }
    __syncthreads();
  }
  if (tid == 0) {
    wsf[0] = r0[0];
    wsf[1] = r1[0];
    wsf[2] = r2[0];
    wsi[5] = (int)r3[0];   // n_obj (<=1024, exact in fp32)
  }
}

__global__ __launch_bounds__(256) void k_main(
    const float* __restrict__ bbox_pred,
    const float* __restrict__ lm_pred,
    const float* __restrict__ bbox_tgt,
    const float* __restrict__ lm_tgt,
    float* __restrict__ wsf, int* __restrict__ wsi,
    float* __restrict__ out)
{
  __shared__ float red[256];
  const int tid = threadIdx.x;
  const int bid = blockIdx.x;

  if (bid < NWIN) {
    // landmark duty: one block per target; only winners contribute
    int winner = wsi[16 + bid];
    float val = 0.f;
    if (winner && tid < 68) {
      int cell = wsi[16 + 1024 + bid];
      const float* lp = lm_pred + (long)cell * 136;
      const float* lt = lm_tgt + (long)bid * 136;
      float dx = lt[2 * tid]     - lp[2 * tid];
      float dy = lt[2 * tid + 1] - lp[2 * tid + 1];
      val = sqrtf(dx * dx + dy * dy);
    }
    red[tid] = val;
    __syncthreads();
    for (int s = 128; s > 0; s >>= 1) {
      if (tid < s) red[tid] += red[tid + s];
      __syncthreads();
    }
    if (tid == 0 && winner) {
      const float* bt = bbox_tgt + bid * 5;
      float nf = sqrtf(log1pf(bt[2]) * log1pf(bt[3]));
      atomicAdd(&wsf[3], red[0] / nf);
    }
  } else {
    // conf duty: sum conf^2 over all cells (channel 4, stride 5)
    int cb = bid - NWIN;
    float acc = 0.f;
    for (int i = cb * 256 + tid; i < NCELLS; i += CONF_BLOCKS * 256) {
      float conf = bbox_pred[(long)i * 5 + 4];
      acc += conf * conf;
    }
    red[tid] = acc;
    __syncthreads();
    for (int s = 128; s > 0; s >>= 1) {
      if (tid < s) red[tid] += red[tid + s];
      __syncthreads();
    }
    if (tid == 0) atomicAdd(&wsf[4], red[0]);
  }

  // last-block-done finalize (saves a third dispatch)
  __syncthreads();
  if (tid == 0) {
    __threadfence();
    unsigned done = atomicAdd((unsigned int*)&wsi[6], 1u);
    if (done == (unsigned)(gridDim.x - 1)) {
      float S_all    = atomicAdd(&wsf[4], 0.0f);   // device-scope coherent reads
      float nme_sum  = atomicAdd(&wsf[3], 0.0f);
      float S_obj_sq = wsf[0];   // written by previous dispatch (k_winners)
      float S_obj_m1 = wsf[1];
      float loc_sum  = wsf[2];
      int n_obj_i    = wsi[5];
      float n_obj   = fmaxf((float)n_obj_i, 1.0f);
      float n_noobj = fmaxf((float)(NCELLS - n_obj_i), 1.0f);
      out[0] = 2.0f * nme_sum / (68.0f * n_obj);                       // nme (LAMBDA_LM=2)
      out[1] = 5.0f * loc_sum / (n_obj * 4.0f);                        // loc (LAMBDA_COOR=5)
      out[2] = 0.5f * (S_all - S_obj_sq) / n_noobj + S_obj_m1 / n_obj; // conf (LAMBDA_NOOBJ=0.5)
    }
  }
}

extern "C" void kernel_launch(void* const* d_in, const int* in_sizes, int n_in,
                              void* d_out, int out_size, void* d_ws, size_t ws_size,
                              hipStream_t stream) {
  const float* bbox_pred = (const float*)d_in[0];  // (32,36,36,5,5)
  const float* lm_pred   = (const float*)d_in[1];  // (32,36,36,5,68,2)
  const float* bbox_tgt  = (const float*)d_in[2];  // (32,32,5)
  const float* lm_tgt    = (const float*)d_in[3];  // (32,32,68,2)
  float* wsf = (float*)d_ws;
  int*   wsi = (int*)d_ws;
  float* out = (float*)d_out;

  hipLaunchKernelGGL(k_winners, dim3(1), dim3(1024), 0, stream,
                     bbox_pred, bbox_tgt, wsf, wsi);
  hipLaunchKernelGGL(k_main, dim3(TOTAL_BLOCKS), dim3(256), 0, stream,
                     bbox_pred, lm_pred, bbox_tgt, lm_tgt, wsf, wsi, out);
}

// Round 2
// 167.594 us; speedup vs baseline: 1.1585x; 1.1585x over previous
//
#include <hip/hip_runtime.h>
#include <math.h>

// Problem: B=32, T=32, G=36, A=5 -> NCELLS = 32*36*36*5
#define NCELLS 207360
#define BATCH_BLOCKS 32
#define CONF_BLOCKS 512
#define TOTAL_BLOCKS (BATCH_BLOCKS + CONF_BLOCKS)

// ws layout (floats/ints, zeroed by 64B memset node):
//  f[0]=S_obj_sq  f[1]=S_obj_m1sq  f[2]=loc_sum  f[3]=nme_sum  f[4]=S_all
//  f[5]=n_obj (float)  i[6]=done_counter

__constant__ float c_anc[5] = {0.24f, 0.12f, 0.08f, 0.28f, 0.15f};

// Key = ((gj*36+gi)*5 + best_anchor) for a valid in-bounds target, else -1.
// Mirrors the reference fp32 arithmetic exactly so argmax ties match.
__device__ __forceinline__ int target_key(const float* __restrict__ bt) {
  float v0 = bt[0], v1 = bt[1], v2 = bt[2], v3 = bt[3], v4 = bt[4];
  bool valid = (v0 + v1 + v2 + v3 + v4) != 0.0f;
  int gi = (int)(v0 * 36.0f);
  int gj = (int)(v1 * 36.0f);
  float acx = (0.5f + (float)gi) / 36.0f;
  float acy = (0.5f + (float)gj) / 36.0f;
  float gx1 = (v0 - v2 / 2.0f) * 288.0f;
  float gx2 = (v0 + v2 / 2.0f) * 288.0f;
  float gy1 = (v1 - v3 / 2.0f) * 288.0f;
  float gy2 = (v1 + v3 / 2.0f) * 288.0f;
  float area_g = (gx2 - gx1 + 1.0f) * (gy2 - gy1 + 1.0f);
  int best = 0;
  float best_iou = -3.0e38f;
  for (int a = 0; a < 5; ++a) {
    float aw = c_anc[a];  // anchors are square
    float ax1 = (acx - aw / 2.0f) * 288.0f;
    float ax2 = (acx + aw / 2.0f) * 288.0f;
    float ay1 = (acy - aw / 2.0f) * 288.0f;
    float ay2 = (acy + aw / 2.0f) * 288.0f;
    float ix1 = fmaxf(gx1, ax1);
    float iy1 = fmaxf(gy1, ay1);
    float ix2 = fminf(gx2, ax2);
    float iy2 = fminf(gy2, ay2);
    float inter = (ix2 - ix1 + 1.0f) * (iy2 - iy1 + 1.0f);
    float area_a = (ax2 - ax1 + 1.0f) * (ay2 - ay1 + 1.0f);
    float iou = inter / (area_g + area_a - inter + 1e-16f);
    if (iou > best_iou) { best_iou = iou; best = a; }  // first-max = argmax
  }
  bool inb = valid && (gi >= 0) && (gi < 36) && (gj >= 0) && (gj < 36);
  return inb ? ((gj * 36 + gi) * 5 + best) : -1;
}

__global__ __launch_bounds__(256) void k_fused(
    const float* __restrict__ bbox_pred,   // (32,36,36,5,5)
    const float* __restrict__ lm_pred,     // (32,36,36,5,68,2)
    const float* __restrict__ bbox_tgt,    // (32,32,5)
    const float* __restrict__ lm_tgt,      // (32,32,68,2)
    float* __restrict__ wsf, int* __restrict__ wsi,
    float* __restrict__ out)
{
  __shared__ float red[5][256];
  const int tid = threadIdx.x;
  const int bid = blockIdx.x;

  if (bid < BATCH_BLOCKS) {
    // ---- batch duty: one block per batch b, handles its 32 targets ----
    __shared__ int   skey[32];
    __shared__ int   swin[32];
    __shared__ int   scell[32];
    __shared__ float sinvnf[32];
    const int b = bid;

    if (tid < 32)
      skey[tid] = target_key(bbox_tgt + (b * 32 + tid) * 5);
    __syncthreads();
    if (tid < 32) {
      int key = skey[tid];
      int w = (key >= 0) ? 1 : 0;
      if (w) {  // winner = highest t sharing this cell key (last write wins)
        for (int tt = tid + 1; tt < 32; ++tt)
          if (skey[tt] == key) { w = 0; break; }
      }
      swin[tid]  = w;
      scell[tid] = b * 6480 + key;
      float invnf = 1.0f;
      if (w) {
        const float* bt = bbox_tgt + (b * 32 + tid) * 5;
        invnf = 1.0f / sqrtf(log1pf(bt[2]) * log1pf(bt[3]));
      }
      sinvnf[tid] = invnf;
    }
    __syncthreads();

    // landmark nme partial: 32 targets x 68 landmarks = 2176 elements
    float nme = 0.f;
    for (int idx = tid; idx < 2176; idx += 256) {
      int t = idx / 68;
      int l = idx - t * 68;
      if (swin[t]) {
        const float* lp = lm_pred + (size_t)scell[t] * 136;
        const float* lt = lm_tgt + (size_t)(b * 32 + t) * 136;
        float dx = lt[2 * l]     - lp[2 * l];
        float dy = lt[2 * l + 1] - lp[2 * l + 1];
        nme += sqrtf(dx * dx + dy * dy) * sinvnf[t];
      }
    }

    // winner conf/loc partials (threads 0..31 = targets)
    float csq = 0.f, cm1 = 0.f, loc = 0.f, nw = 0.f;
    if (tid < 32 && swin[tid]) {
      const float* p = bbox_pred + (size_t)scell[tid] * 5;
      float conf = p[4];
      csq = conf * conf;
      float cm = conf - 1.0f;
      cm1 = cm * cm;
      const float* bt = bbox_tgt + (b * 32 + tid) * 5;
      float gs[4] = {log1pf(bt[0]), log1pf(bt[1]), log1pf(bt[2]), log1pf(bt[3])};
      for (int c = 0; c < 4; ++c) {
        float d = p[c] - gs[c];
        float ad = fabsf(d);
        loc += (ad < 1.0f) ? (0.5f * d * d) : (ad - 0.5f);
      }
      nw = 1.0f;
    }

    red[0][tid] = csq; red[1][tid] = cm1; red[2][tid] = loc;
    red[3][tid] = nme; red[4][tid] = nw;
    __syncthreads();
    for (int s = 128; s > 0; s >>= 1) {
      if (tid < s)
        for (int q = 0; q < 5; ++q) red[q][tid] += red[q][tid + s];
      __syncthreads();
    }
    if (tid == 0) {
      atomicAdd(&wsf[0], red[0][0]);
      atomicAdd(&wsf[1], red[1][0]);
      atomicAdd(&wsf[2], red[2][0]);
      atomicAdd(&wsf[3], red[3][0]);
      atomicAdd(&wsf[5], red[4][0]);
    }
  } else {
    // ---- conf duty: sum conf^2 over all cells (channel 4, stride 5) ----
    int cb = bid - BATCH_BLOCKS;
    float acc = 0.f;
    for (int i = cb * 256 + tid; i < NCELLS; i += CONF_BLOCKS * 256) {
      float conf = bbox_pred[(size_t)i * 5 + 4];
      acc += conf * conf;
    }
    red[0][tid] = acc;
    __syncthreads();
    for (int s = 128; s > 0; s >>= 1) {
      if (tid < s) red[0][tid] += red[0][tid + s];
      __syncthreads();
    }
    if (tid == 0) atomicAdd(&wsf[4], red[0][0]);
  }

  // ---- last-block-done finalize ----
  __syncthreads();
  if (tid == 0) {
    __threadfence();
    unsigned done = atomicAdd((unsigned int*)&wsi[6], 1u);
    if (done == (unsigned)(TOTAL_BLOCKS - 1)) {
      __threadfence();
      // all accumulators were written via device-scope atomics; read the same way
      float S_obj_sq = atomicAdd(&wsf[0], 0.0f);
      float S_obj_m1 = atomicAdd(&wsf[1], 0.0f);
      float loc_sum  = atomicAdd(&wsf[2], 0.0f);
      float nme_sum  = atomicAdd(&wsf[3], 0.0f);
      float S_all    = atomicAdd(&wsf[4], 0.0f);
      float n_obj_f  = atomicAdd(&wsf[5], 0.0f);
      float n_obj   = fmaxf(n_obj_f, 1.0f);
      float n_noobj = fmaxf((float)NCELLS - n_obj_f, 1.0f);
      out[0] = 2.0f * nme_sum / (68.0f * n_obj);                       // nme   (LAMBDA_LM=2)
      out[1] = 5.0f * loc_sum / (n_obj * 4.0f);                        // loc   (LAMBDA_COOR=5)
      out[2] = 0.5f * (S_all - S_obj_sq) / n_noobj + S_obj_m1 / n_obj; // conf  (LAMBDA_NOOBJ=0.5)
    }
  }
}

extern "C" void kernel_launch(void* const* d_in, const int* in_sizes, int n_in,
                              void* d_out, int out_size, void* d_ws, size_t ws_size,
                              hipStream_t stream) {
  const float* bbox_pred = (const float*)d_in[0];
  const float* lm_pred   = (const float*)d_in[1];
  const float* bbox_tgt  = (const float*)d_in[2];
  const float* lm_tgt    = (const float*)d_in[3];
  float* wsf = (float*)d_ws;
  int*   wsi = (int*)d_ws;
  float* out = (float*)d_out;

  // zero the 7 accumulator slots + done counter (graph-legal memset node)
  hipMemsetAsync(d_ws, 0, 64, stream);
  hipLaunchKernelGGL(k_fused, dim3(TOTAL_BLOCKS), dim3(256), 0, stream,
                     bbox_pred, lm_pred, bbox_tgt, lm_tgt, wsf, wsi, out);
}